// Round 15
// baseline (192.131 us; speedup 1.0000x reference)
//
#include <hip/hip_runtime.h>
#include <hip/hip_bf16.h>

// y(x) = levels[ #{j : b[j] < x} ], levels = [0, cumsum(scale)],
// b[j] = cumsum[j] - scale[j]*0.5 (contraction OFF: matches reference
// mul-then-sub rounding at bucket boundaries; partial sums identical to
// jnp.cumsum sequential order).
//
// Round 15 probe: FORCED 8-deep per-wave load pipeline via inline asm.
// r8's C++ MLP=8 was re-serialized by the compiler (VGPR_Count=32, ~2 live
// buffers). Here 8 asm global_load_dwordx4 with forced-live "=v" quads issue
// back-to-back; counted s_waitcnt vmcnt(7-k) + sched_barrier(0) + "+v" tie
// releases one chunk at a time while the rest stay in flight. Layout: each
// wave owns 512 consecutive f4 (8 chunks x 64 f4); chunks addressed as two
// base pairs + imm offset:0..3072 (13-bit signed limit).

typedef float vfloat4 __attribute__((ext_vector_type(4)));

__device__ __forceinline__ unsigned qidx_asm(float x, const float* __restrict__ b) {
    unsigned idx;
    asm("v_mov_b32 %0, 0\n\t"
        "v_cmp_lt_f32 vcc, %1, %16\n\t"
        "v_addc_co_u32 %0, vcc, %0, 0, vcc\n\t"
        "v_cmp_lt_f32 vcc, %2, %16\n\t"
        "v_addc_co_u32 %0, vcc, %0, 0, vcc\n\t"
        "v_cmp_lt_f32 vcc, %3, %16\n\t"
        "v_addc_co_u32 %0, vcc, %0, 0, vcc\n\t"
        "v_cmp_lt_f32 vcc, %4, %16\n\t"
        "v_addc_co_u32 %0, vcc, %0, 0, vcc\n\t"
        "v_cmp_lt_f32 vcc, %5, %16\n\t"
        "v_addc_co_u32 %0, vcc, %0, 0, vcc\n\t"
        "v_cmp_lt_f32 vcc, %6, %16\n\t"
        "v_addc_co_u32 %0, vcc, %0, 0, vcc\n\t"
        "v_cmp_lt_f32 vcc, %7, %16\n\t"
        "v_addc_co_u32 %0, vcc, %0, 0, vcc\n\t"
        "v_cmp_lt_f32 vcc, %8, %16\n\t"
        "v_addc_co_u32 %0, vcc, %0, 0, vcc\n\t"
        "v_cmp_lt_f32 vcc, %9, %16\n\t"
        "v_addc_co_u32 %0, vcc, %0, 0, vcc\n\t"
        "v_cmp_lt_f32 vcc, %10, %16\n\t"
        "v_addc_co_u32 %0, vcc, %0, 0, vcc\n\t"
        "v_cmp_lt_f32 vcc, %11, %16\n\t"
        "v_addc_co_u32 %0, vcc, %0, 0, vcc\n\t"
        "v_cmp_lt_f32 vcc, %12, %16\n\t"
        "v_addc_co_u32 %0, vcc, %0, 0, vcc\n\t"
        "v_cmp_lt_f32 vcc, %13, %16\n\t"
        "v_addc_co_u32 %0, vcc, %0, 0, vcc\n\t"
        "v_cmp_lt_f32 vcc, %14, %16\n\t"
        "v_addc_co_u32 %0, vcc, %0, 0, vcc\n\t"
        "v_cmp_lt_f32 vcc, %15, %16\n\t"
        "v_addc_co_u32 %0, vcc, %0, 0, vcc"
        : "=&v"(idx)
        : "v"(b[0]), "v"(b[1]), "v"(b[2]), "v"(b[3]), "v"(b[4]),
          "v"(b[5]), "v"(b[6]), "v"(b[7]), "v"(b[8]), "v"(b[9]),
          "v"(b[10]), "v"(b[11]), "v"(b[12]), "v"(b[13]), "v"(b[14]),
          "v"(x)
        : "vcc");
    return idx;
}

// Issue one 16B load with immediate byte offset (must be literal 0..4095).
#define LOADK(dst, base, OFF)                                               \
    asm volatile("global_load_dwordx4 %0, %1, off offset:" #OFF             \
                 : "=v"(dst) : "v"(base))

// Release chunk: wait until <=N vmem ops outstanding, tie the chunk's regs
// through the asm (real dependency), then fence the scheduler (rule #18).
#define WAITV(N, reg)                                                       \
    asm volatile("s_waitcnt vmcnt(" #N ")" : "+v"(reg)::"memory");          \
    __builtin_amdgcn_sched_barrier(0)

#define STOREK(src, base, OFF)                                              \
    asm volatile("global_store_dwordx4 %0, %1, off offset:" #OFF            \
                 :: "v"(base), "v"(src) : "memory")

__global__ __launch_bounds__(256) void nulsq_quant_kernel(
    const float* __restrict__ x, const float* __restrict__ scale,
    float* __restrict__ y, int n4, int n, int full_blocks) {
#pragma clang fp contract(off)
    __shared__ float levels[16];

    float b[15];
    {
        float c = 0.0f;
#pragma unroll
        for (int j = 0; j < 15; ++j) {
            float s = scale[j];       // uniform broadcast loads
            c = c + s;                // cumsum[j], sequential == jnp.cumsum
            b[j] = c - s * 0.5f;      // mul then sub, no fma
        }
    }
    if (threadIdx.x == 0) {
        float c = 0.0f;
        levels[0] = 0.0f;
#pragma unroll
        for (int j = 0; j < 15; ++j) {
            c = c + scale[j];
            levels[j + 1] = c;        // identical partial sums as reference
        }
    }
    __syncthreads();

    const vfloat4* __restrict__ x4 = reinterpret_cast<const vfloat4*>(x);
    vfloat4* __restrict__ y4 = reinterpret_cast<vfloat4*>(y);

    const int bx = (int)blockIdx.x;
    const int wave = (int)threadIdx.x >> 6;
    const int lane = (int)threadIdx.x & 63;
    // Each wave owns 512 consecutive f4; 8 chunks of 64 f4 (1 KB/wave-instr,
    // perfectly coalesced). Block = 4 waves = 2048 f4.
    const int f4base = bx * 2048 + wave * 512 + lane;

    if (bx < full_blocks) {
        const vfloat4* px0 = x4 + f4base;        // chunks 0..3 (offset 0..3072)
        const vfloat4* px4 = px0 + 256;          // chunks 4..7 (offset 0..3072)
        vfloat4* py0 = y4 + f4base;
        vfloat4* py4 = py0 + 256;

        vfloat4 v0, v1, v2, v3, v4, v5, v6, v7;
        LOADK(v0, px0, 0);
        LOADK(v1, px0, 1024);
        LOADK(v2, px0, 2048);
        LOADK(v3, px0, 3072);
        LOADK(v4, px4, 0);
        LOADK(v5, px4, 1024);
        LOADK(v6, px4, 2048);
        LOADK(v7, px4, 3072);

        vfloat4 r;
#define CHUNK(vk, pb, OFF)                        \
        r.x = levels[qidx_asm(vk.x, b)];          \
        r.y = levels[qidx_asm(vk.y, b)];          \
        r.z = levels[qidx_asm(vk.z, b)];          \
        r.w = levels[qidx_asm(vk.w, b)];          \
        STOREK(r, pb, OFF)

        WAITV(7, v0); CHUNK(v0, py0, 0);
        WAITV(6, v1); CHUNK(v1, py0, 1024);
        WAITV(5, v2); CHUNK(v2, py0, 2048);
        WAITV(4, v3); CHUNK(v3, py0, 3072);
        WAITV(3, v4); CHUNK(v4, py4, 0);
        WAITV(2, v5); CHUNK(v5, py4, 1024);
        WAITV(1, v6); CHUNK(v6, py4, 2048);
        WAITV(0, v7); CHUNK(v7, py4, 3072);
#undef CHUNK
    } else {
        // Generic guarded path (partial block only; not hit for this shape).
        int end = (bx + 1) * 2048;
        if (end > n4) end = n4;
        for (int i = bx * 2048 + (int)threadIdx.x; i < end; i += 256) {
            vfloat4 v = x4[i];
            vfloat4 r;
            r.x = levels[qidx_asm(v.x, b)];
            r.y = levels[qidx_asm(v.y, b)];
            r.z = levels[qidx_asm(v.z, b)];
            r.w = levels[qidx_asm(v.w, b)];
            y4[i] = r;
        }
    }

    // Scalar remainder for n % 4 != 0 (not hit for this shape).
    if (bx == (int)gridDim.x - 1) {
        int t = n4 * 4 + (int)threadIdx.x;
        if (t < n) y[t] = levels[qidx_asm(x[t], b)];
    }
}

extern "C" void kernel_launch(void* const* d_in, const int* in_sizes, int n_in,
                              void* d_out, int out_size, void* d_ws, size_t ws_size,
                              hipStream_t stream) {
    const float* x = (const float*)d_in[0];
    const float* scale = (const float*)d_in[1];
    float* y = (float*)d_out;

    int n = in_sizes[0];
    int n4 = n / 4;

    const int block = 256;
    const int f4_per_block = block * 8;            // 2048
    int full_blocks = n4 / f4_per_block;           // 3136 for this shape (exact)
    int grid = (n4 + f4_per_block - 1) / f4_per_block;
    if (grid < 1) grid = 1;

    nulsq_quant_kernel<<<grid, block, 0, stream>>>(x, scale, y, n4, n, full_blocks);
}